// Round 9
// baseline (163.052 us; speedup 1.0000x reference)
//
#include <hip/hip_runtime.h>
#include <hip/hip_bf16.h>

#define NN 8192
#define DD 128

typedef __attribute__((ext_vector_type(8))) short short8;
typedef __attribute__((ext_vector_type(4))) float f32x4;

__device__ __forceinline__ unsigned short f2bf(float x) {
    unsigned u = __float_as_uint(x);
    u += 0x7FFFu + ((u >> 16) & 1u);   // round-to-nearest-even
    return (unsigned short)(u >> 16);
}
__device__ __forceinline__ float bf2f(unsigned short b) {
    return __uint_as_float(((unsigned)b) << 16);
}

// Cast emb -> bf16 (ws) and compute row sq-norms FROM THE BF16 VALUES.
__global__ void prep_kernel(const float* __restrict__ emb,
                            unsigned short* __restrict__ ebf,
                            float* __restrict__ nrm) {
    int row  = blockIdx.x * 4 + (threadIdx.x >> 6);   // 1 wave per row
    int lane = threadIdx.x & 63;
    const float2 v = *reinterpret_cast<const float2*>(emb + (size_t)row * DD + lane * 2);
    unsigned short b0 = f2bf(v.x), b1 = f2bf(v.y);
    ushort2 st; st.x = b0; st.y = b1;
    *reinterpret_cast<ushort2*>(ebf + (size_t)row * DD + lane * 2) = st;
    float f0 = bf2f(b0), f1 = bf2f(b1);
    float s = f0 * f0 + f1 * f1;
    #pragma unroll
    for (int m = 32; m; m >>= 1) s += __shfl_xor(s, m);
    if (lane == 0) nrm[row] = s;
}

// Row-major W streaming: block owns j-strip [j0, j0+16) and streams ALL i.
// W rows j0..j0+15 = 512 KB CONTIGUOUS, consumed sequentially (DRAM-page
// friendly, memcpy-like). B-frags (16 j-rows) are loop-invariant registers;
// A-frags stream from L2-resident ebf. W pairs with acc as per-lane float4
// (gj = j0+lr is the fragment row). 4-set register pipeline, depth 3.
// Wave w handles chunks c = w + 4k (16 i each), k = 0..127.

#define ISSUE(S)                                                               \
  {                                                                            \
    w4##S = *reinterpret_cast<const f32x4*>(pW);                               \
    af##S[0] = *reinterpret_cast<const short8*>(pA);                           \
    af##S[1] = *reinterpret_cast<const short8*>(pA + 32);                      \
    af##S[2] = *reinterpret_cast<const short8*>(pA + 64);                      \
    af##S[3] = *reinterpret_cast<const short8*>(pA + 96);                      \
    ni##S = *reinterpret_cast<const f32x4*>(pN);                               \
    pW += 64; pA += (size_t)64 * DD; pN += 64;                                 \
  }

#define COMPUTE(S)                                                             \
  {                                                                            \
    f32x4 acc = (f32x4){0.f, 0.f, 0.f, 0.f};                                   \
    acc = __builtin_amdgcn_mfma_f32_16x16x32_bf16(af##S[0], bf[0], acc,0,0,0); \
    acc = __builtin_amdgcn_mfma_f32_16x16x32_bf16(af##S[1], bf[1], acc,0,0,0); \
    acc = __builtin_amdgcn_mfma_f32_16x16x32_bf16(af##S[2], bf[2], acc,0,0,0); \
    acc = __builtin_amdgcn_mfma_f32_16x16x32_bf16(af##S[3], bf[3], acc,0,0,0); \
    _Pragma("unroll")                                                          \
    for (int r = 0; r < 4; ++r) {                                              \
      float sq = ni##S[r] + njv - 2.0f * acc[r];                               \
      float d  = sqrtf(fmaxf(sq, 0.0f));                                       \
      sW += w4##S[r]; sDW += w4##S[r] * d; dmax = fmaxf(dmax, d);              \
    }                                                                          \
  }

#define BODY(C, I) { ISSUE(I); __builtin_amdgcn_sched_barrier(0); COMPUTE(C); }

__global__ __launch_bounds__(256, 2)
void gram_kernel(const unsigned short* __restrict__ ebf,
                 const float* __restrict__ nrm,
                 const float* __restrict__ W,
                 float4* __restrict__ part) {
    const int wave = threadIdx.x >> 6;
    const int lane = threadIdx.x & 63;
    const int lr = lane & 15;
    const int hi = lane >> 4;
    const int j0 = blockIdx.x * 16;

    // Loop-invariant B fragments (16 j-rows) + col norm.
    short8 bf[4];
    #pragma unroll
    for (int kc = 0; kc < 4; ++kc)
        bf[kc] = *reinterpret_cast<const short8*>(
            ebf + (size_t)(j0 + lr) * DD + kc * 32 + hi * 8);
    const float njv = nrm[j0 + lr];

    // Running pointers for this wave's chunk stream (c = wave + 4k).
    const float* pW = W + (size_t)(j0 + lr) * NN + wave * 16 + hi * 4;
    const unsigned short* pA = ebf + (size_t)(wave * 16 + lr) * DD + hi * 8;
    const float* pN = nrm + wave * 16 + hi * 4;

    short8 af0[4], af1[4], af2[4], af3[4];
    f32x4 w40, w41, w42, w43;
    f32x4 ni0, ni1, ni2, ni3;
    float sW = 0.f, sDW = 0.f, dmax = 0.f;

    // Prologue: fill sets 0,1,2 (chunks k=0,1,2 for this wave).
    ISSUE(0); ISSUE(1); ISSUE(2);
    __builtin_amdgcn_sched_barrier(0);

    // 31 full rounds of 4 chunks; body k issues chunk k+3 into set (k+3)&3.
    for (int r = 0; r < 31; ++r) {
        BODY(0, 3); BODY(1, 0); BODY(2, 1); BODY(3, 2);
    }
    // Final round: k=124 issues the last chunk (127); then drain.
    BODY(0, 3);
    COMPUTE(1); COMPUTE(2); COMPUTE(3);

    #pragma unroll
    for (int m = 32; m; m >>= 1) {
        sW  += __shfl_xor(sW, m);
        sDW += __shfl_xor(sDW, m);
        dmax = fmaxf(dmax, __shfl_xor(dmax, m));
    }
    __shared__ float sw_s[4], sdw_s[4], dm_s[4];
    if (lane == 0) { sw_s[wave] = sW; sdw_s[wave] = sDW; dm_s[wave] = dmax; }
    __syncthreads();
    if (threadIdx.x == 0) {
        float SW = 0.f, SDW = 0.f, DM = 0.f;
        #pragma unroll
        for (int k = 0; k < 4; ++k) {
            SW += sw_s[k]; SDW += sdw_s[k]; DM = fmaxf(DM, dm_s[k]);
        }
        float4 p; p.x = SW; p.y = SDW; p.z = DM; p.w = 0.f;
        part[blockIdx.x] = p;
    }
}

// Single block: reduce per-block partials in fp64, emit the loss.
__global__ __launch_bounds__(512)
void reduce_kernel(const float4* __restrict__ part, int nblk,
                   float* __restrict__ out) {
    const int tid = threadIdx.x;
    double sW = 0.0, sDW = 0.0;
    float dmax = 0.f;
    for (int idx = tid; idx < nblk; idx += 512) {
        float4 p = part[idx];
        sW += (double)p.x; sDW += (double)p.y; dmax = fmaxf(dmax, p.z);
    }
    #pragma unroll
    for (int m = 32; m; m >>= 1) {
        sW  += __shfl_xor(sW, m);
        sDW += __shfl_xor(sDW, m);
        dmax = fmaxf(dmax, __shfl_xor(dmax, m));
    }
    __shared__ double sw_s[8], sdw_s[8];
    __shared__ float dm_s[8];
    const int w = tid >> 6, l = tid & 63;
    if (l == 0) { sw_s[w] = sW; sdw_s[w] = sDW; dm_s[w] = dmax; }
    __syncthreads();
    if (tid == 0) {
        double SW = 0.0, SDW = 0.0; float DM = 0.f;
        #pragma unroll
        for (int k = 0; k < 8; ++k) {
            SW += sw_s[k]; SDW += sdw_s[k]; DM = fmaxf(DM, dm_s[k]);
        }
        out[0] = (float)((SW - SDW / (double)DM) / ((double)NN * (double)NN));
    }
}

extern "C" void kernel_launch(void* const* d_in, const int* in_sizes, int n_in,
                              void* d_out, int out_size, void* d_ws, size_t ws_size,
                              hipStream_t stream) {
    const float* emb = (const float*)d_in[0];
    const float* W   = (const float*)d_in[1];
    float* out = (float*)d_out;

    char* ws = (char*)d_ws;
    float4* part        = (float4*)ws;                               // 8 KB (512 x 16B)
    unsigned short* ebf = (unsigned short*)(ws + 16384);             // 2 MB bf16 emb
    float* nrm          = (float*)(ws + 16384 + (size_t)NN * DD * 2);// 32 KB norms

    prep_kernel<<<NN / 4, 256, 0, stream>>>(emb, ebf, nrm);
    gram_kernel<<<NN / 16, 256, 0, stream>>>(ebf, nrm, W, part);     // 512 blocks
    reduce_kernel<<<1, 512, 0, stream>>>(part, NN / 16, out);
}

// Round 10
// 92.877 us; speedup vs baseline: 1.7556x; 1.7556x over previous
//
#include <hip/hip_runtime.h>
#include <hip/hip_bf16.h>

#define NN 8192
#define DD 128
#define JTPB 16   // j-tiles (64 wide) per block
#define NBLK 512

typedef __attribute__((ext_vector_type(8))) short short8;
typedef __attribute__((ext_vector_type(4))) float f32x4;

__device__ __forceinline__ unsigned short f2bf(float x) {
    unsigned u = __float_as_uint(x);
    u += 0x7FFFu + ((u >> 16) & 1u);   // round-to-nearest-even
    return (unsigned short)(u >> 16);
}
__device__ __forceinline__ float bf2f(unsigned short b) {
    return __uint_as_float(((unsigned)b) << 16);
}

// Cast emb -> bf16 (ws) and compute row sq-norms FROM THE BF16 VALUES.
// Also zeroes the gram completion counter (stream-ordered before gram).
__global__ void prep_kernel(const float* __restrict__ emb,
                            unsigned short* __restrict__ ebf,
                            float* __restrict__ nrm,
                            unsigned int* __restrict__ done) {
    if (blockIdx.x == 0 && threadIdx.x == 0)
        __hip_atomic_store(done, 0u, __ATOMIC_RELAXED, __HIP_MEMORY_SCOPE_AGENT);
    int row  = blockIdx.x * 4 + (threadIdx.x >> 6);   // 1 wave per row
    int lane = threadIdx.x & 63;
    const float2 v = *reinterpret_cast<const float2*>(emb + (size_t)row * DD + lane * 2);
    unsigned short b0 = f2bf(v.x), b1 = f2bf(v.y);
    ushort2 st; st.x = b0; st.y = b1;
    *reinterpret_cast<ushort2*>(ebf + (size_t)row * DD + lane * 2) = st;
    float f0 = bf2f(b0), f1 = bf2f(b1);
    float s = f0 * f0 + f1 * f1;
    #pragma unroll
    for (int m = 32; m; m >>= 1) s += __shfl_xor(s, m);
    if (lane == 0) nrm[row] = s;
}

// R4 structure (best verified: 128i x 64j tiles, 4 waves 2x2, double-buffered
// LDS, barriered 1-deep prefetch) with ONE staging change: W tile loads are
// NON-TEMPORAL register loads (bypass L2 allocation for the single-use
// stream) + swizzled ds_write_b128, instead of global_load_lds. Epilogue
// reads W^T from LDS (bank-even b128) and pairs with MFMA acc:
// dist = sqrt(max(0, ni + nj - 2*dot)). Final reduction fused via
// last-block pattern (no separate reduce kernel).
__global__ __launch_bounds__(256, 2)
void gram_kernel(const unsigned short* __restrict__ ebf,
                 const float* __restrict__ nrm,
                 const float* __restrict__ W,
                 float4* __restrict__ part,
                 unsigned int* __restrict__ done,
                 float* __restrict__ out) {
    __shared__ float wlds[2][64 * 128];   // 2 x 32 KB W tiles
    __shared__ float sw_s[4], sdw_s[4], dm_s[4];
    __shared__ double swd[4], sdwd[4];
    __shared__ float dmf[4];
    __shared__ int last_s;

    const int wave = threadIdx.x >> 6;
    const int lane = threadIdx.x & 63;
    const int wRow = wave >> 1;          // 0..1 : i half (64 rows)
    const int wCol = wave & 1;           // 0..1 : j half (32 cols)
    const int i0  = blockIdx.y * 128;
    const int jc0 = blockIdx.x * (JTPB * 64);

    const int lr = lane & 15;
    const int hi = lane >> 4;
    const int lk = hi * 8;

    // Stage coords: thread covers rows r*8+trow (r=0..7), chunk tc (contig
    // source); LDS write position = tc ^ (row&7) = tc ^ trow (involution).
    const int trow = threadIdx.x >> 5;          // 0..7
    const int tc   = threadIdx.x & 31;
    const int swz4 = ((tc ^ trow) * 4);         // swizzled float offset
    const float* wbase = W + (size_t)i0 + tc * 4;

    // A fragments (this block's 128 i-rows, wave's 64) + row norms.
    short8 af[4][4];
    #pragma unroll
    for (int kc = 0; kc < 4; ++kc)
        #pragma unroll
        for (int m = 0; m < 4; ++m)
            af[kc][m] = *reinterpret_cast<const short8*>(
                ebf + (size_t)(i0 + wRow * 64 + m * 16 + lr) * DD + kc * 32 + lk);
    f32x4 ni4[4];
    #pragma unroll
    for (int m = 0; m < 4; ++m)
        ni4[m] = *reinterpret_cast<const f32x4*>(nrm + i0 + wRow * 64 + m * 16 + hi * 4);

    // Prologue: stage tile 0 (NT load -> swizzled LDS write).
    {
        f32x4 w0[8];
        #pragma unroll
        for (int r = 0; r < 8; ++r)
            w0[r] = __builtin_nontemporal_load(reinterpret_cast<const f32x4*>(
                wbase + (size_t)(jc0 + r * 8 + trow) * NN));
        #pragma unroll
        for (int r = 0; r < 8; ++r)
            *reinterpret_cast<f32x4*>(&wlds[0][(r * 8 + trow) * 128 + swz4]) = w0[r];
    }
    __syncthreads();

    float sW = 0.f, sDW = 0.f, dmax = 0.f;

    for (int t = 0; t < JTPB; ++t) {
        const int j0t = jc0 + t * 64;
        const int jw  = j0t + wCol * 32;
        const int cb  = t & 1;

        // B fragments + col norms for THIS tile (cached loads, L2-resident).
        short8 bf[4][2];
        #pragma unroll
        for (int kc = 0; kc < 4; ++kc)
            #pragma unroll
            for (int n = 0; n < 2; ++n)
                bf[kc][n] = *reinterpret_cast<const short8*>(
                    ebf + (size_t)(jw + n * 16 + lr) * DD + kc * 32 + lk);
        float nj[2];
        #pragma unroll
        for (int n = 0; n < 2; ++n) nj[n] = nrm[jw + n * 16 + lr];

        __builtin_amdgcn_sched_barrier(0);
        // NT prefetch tile t+1 into registers (early issue; lands under MFMA
        // + epilogue; consumed by ds_write just before the barrier).
        f32x4 wreg[8];
        const bool more = (t + 1 < JTPB);
        if (more) {
            #pragma unroll
            for (int r = 0; r < 8; ++r)
                wreg[r] = __builtin_nontemporal_load(reinterpret_cast<const f32x4*>(
                    wbase + (size_t)(j0t + 64 + r * 8 + trow) * NN));
        }
        __builtin_amdgcn_sched_barrier(0);

        // Gram MFMA: wave tile 64(i) x 32(j), K=128.
        f32x4 acc[4][2];
        #pragma unroll
        for (int m = 0; m < 4; ++m)
            #pragma unroll
            for (int n = 0; n < 2; ++n) acc[m][n] = (f32x4){0.f, 0.f, 0.f, 0.f};
        #pragma unroll
        for (int kc = 0; kc < 4; ++kc)
            #pragma unroll
            for (int m = 0; m < 4; ++m)
                #pragma unroll
                for (int n = 0; n < 2; ++n)
                    acc[m][n] = __builtin_amdgcn_mfma_f32_16x16x32_bf16(
                        af[kc][m], bf[kc][n], acc[m][n], 0, 0, 0);

        // Epilogue: W^T from LDS[cb] (swizzled, bank-even), accumulate.
        #pragma unroll
        for (int m = 0; m < 4; ++m) {
            #pragma unroll
            for (int n = 0; n < 2; ++n) {
                const int jp = wCol * 32 + n * 16 + lr;
                const int c0 = wRow * 16 + m * 4 + hi;
                const f32x4 w4 = *reinterpret_cast<const f32x4*>(
                    &wlds[cb][jp * 128 + ((c0 ^ (jp & 7)) * 4)]);
                #pragma unroll
                for (int r = 0; r < 4; ++r) {
                    float sq = ni4[m][r] + nj[n] - 2.0f * acc[m][n][r];
                    sq = fmaxf(sq, 0.0f);
                    float d = sqrtf(sq);
                    sW  += w4[r];
                    sDW += w4[r] * d;
                    dmax = fmaxf(dmax, d);
                }
            }
        }

        __builtin_amdgcn_sched_barrier(0);
        // Write staged tile t+1 into the other buffer (compiler inserts the
        // vmcnt waits for wreg deps), then barrier makes it visible.
        if (more) {
            float* dst = &wlds[cb ^ 1][0];
            #pragma unroll
            for (int r = 0; r < 8; ++r)
                *reinterpret_cast<f32x4*>(&dst[(r * 8 + trow) * 128 + swz4]) = wreg[r];
        }
        __syncthreads();
    }

    #pragma unroll
    for (int m = 32; m; m >>= 1) {
        sW  += __shfl_xor(sW, m);
        sDW += __shfl_xor(sDW, m);
        dmax = fmaxf(dmax, __shfl_xor(dmax, m));
    }
    if (lane == 0) { sw_s[wave] = sW; sdw_s[wave] = sDW; dm_s[wave] = dmax; }
    __syncthreads();

    const int bid = blockIdx.y * gridDim.x + blockIdx.x;
    if (threadIdx.x == 0) {
        float SW = 0.f, SDW = 0.f, DM = 0.f;
        #pragma unroll
        for (int k = 0; k < 4; ++k) {
            SW += sw_s[k]; SDW += sdw_s[k]; DM = fmaxf(DM, dm_s[k]);
        }
        float4 p; p.x = SW; p.y = SDW; p.z = DM; p.w = 0.f;
        part[bid] = p;
        __threadfence();                                 // release partial
        unsigned prev = atomicAdd(done, 1u);             // device-scope
        last_s = (prev == NBLK - 1) ? 1 : 0;
    }
    __syncthreads();

    // Last block: fused final reduction (AGENT-scope loads see all partials).
    if (last_s) {
        __threadfence();                                 // acquire
        double SW = 0.0, SDW = 0.0;
        float DM = 0.f;
        for (int idx = threadIdx.x; idx < NBLK; idx += 256) {
            const float* p = reinterpret_cast<const float*>(part + idx);
            float x = __hip_atomic_load(p + 0, __ATOMIC_RELAXED, __HIP_MEMORY_SCOPE_AGENT);
            float y = __hip_atomic_load(p + 1, __ATOMIC_RELAXED, __HIP_MEMORY_SCOPE_AGENT);
            float z = __hip_atomic_load(p + 2, __ATOMIC_RELAXED, __HIP_MEMORY_SCOPE_AGENT);
            SW += (double)x; SDW += (double)y; DM = fmaxf(DM, z);
        }
        #pragma unroll
        for (int m = 32; m; m >>= 1) {
            SW  += __shfl_xor(SW, m);
            SDW += __shfl_xor(SDW, m);
            DM = fmaxf(DM, __shfl_xor(DM, m));
        }
        if (lane == 0) { swd[wave] = SW; sdwd[wave] = SDW; dmf[wave] = DM; }
        __syncthreads();
        if (threadIdx.x == 0) {
            double TSW = 0.0, TSDW = 0.0; float TDM = 0.f;
            #pragma unroll
            for (int k = 0; k < 4; ++k) {
                TSW += swd[k]; TSDW += sdwd[k]; TDM = fmaxf(TDM, dmf[k]);
            }
            out[0] = (float)((TSW - TSDW / (double)TDM) / ((double)NN * (double)NN));
        }
    }
}

extern "C" void kernel_launch(void* const* d_in, const int* in_sizes, int n_in,
                              void* d_out, int out_size, void* d_ws, size_t ws_size,
                              hipStream_t stream) {
    const float* emb = (const float*)d_in[0];
    const float* W   = (const float*)d_in[1];
    float* out = (float*)d_out;

    char* ws = (char*)d_ws;
    float4* part        = (float4*)ws;                               // 8 KB (512 x 16B)
    unsigned int* done  = (unsigned int*)(ws + 8192);                // 4 B counter
    unsigned short* ebf = (unsigned short*)(ws + 16384);             // 2 MB bf16 emb
    float* nrm          = (float*)(ws + 16384 + (size_t)NN * DD * 2);// 32 KB norms

    prep_kernel<<<NN / 4, 256, 0, stream>>>(emb, ebf, nrm, done);
    dim3 grid(NN / (64 * JTPB), NN / 128);   // 8 x 64 = 512 blocks (2/CU)
    gram_kernel<<<grid, 256, 0, stream>>>(ebf, nrm, W, part, done, out);
}

// Round 11
// 83.990 us; speedup vs baseline: 1.9413x; 1.1058x over previous
//
#include <hip/hip_runtime.h>
#include <hip/hip_bf16.h>

#define NN 8192
#define DD 128
#define JTPB 16   // j-tiles (64 wide) per block
#define NBLK 512

typedef __attribute__((ext_vector_type(8))) short short8;
typedef __attribute__((ext_vector_type(4))) float f32x4;

__device__ __forceinline__ unsigned short f2bf(float x) {
    unsigned u = __float_as_uint(x);
    u += 0x7FFFu + ((u >> 16) & 1u);   // round-to-nearest-even
    return (unsigned short)(u >> 16);
}
__device__ __forceinline__ float bf2f(unsigned short b) {
    return __uint_as_float(((unsigned)b) << 16);
}

__device__ __forceinline__ void gld_lds16(const float* src, float* ldst) {
    __builtin_amdgcn_global_load_lds(
        (const __attribute__((address_space(1))) void*)src,
        (__attribute__((address_space(3))) void*)ldst, 16, 0, 0);
}

// Cast emb -> bf16 (ws) and compute row sq-norms FROM THE BF16 VALUES.
// Also zeroes the gram completion counter (stream-ordered before gram).
__global__ void prep_kernel(const float* __restrict__ emb,
                            unsigned short* __restrict__ ebf,
                            float* __restrict__ nrm,
                            unsigned int* __restrict__ done) {
    if (blockIdx.x == 0 && threadIdx.x == 0)
        __hip_atomic_store(done, 0u, __ATOMIC_RELAXED, __HIP_MEMORY_SCOPE_AGENT);
    int row  = blockIdx.x * 4 + (threadIdx.x >> 6);   // 1 wave per row
    int lane = threadIdx.x & 63;
    const float2 v = *reinterpret_cast<const float2*>(emb + (size_t)row * DD + lane * 2);
    unsigned short b0 = f2bf(v.x), b1 = f2bf(v.y);
    ushort2 st; st.x = b0; st.y = b1;
    *reinterpret_cast<ushort2*>(ebf + (size_t)row * DD + lane * 2) = st;
    float f0 = bf2f(b0), f1 = bf2f(b1);
    float s = f0 * f0 + f1 * f1;
    #pragma unroll
    for (int m = 32; m; m >>= 1) s += __shfl_xor(s, m);
    if (lane == 0) nrm[row] = s;
}

// R4 structure exactly (best verified: 128i x 64j tiles, 4 waves 2x2,
// global_load_lds staging w/ chunk-XOR swizzle, double-buffered, barriered
// 1-deep prefetch) + fused last-block final reduction (saves the reduce
// kernel launch). Epilogue reads W^T from LDS (bank-even b128), pairs with
// MFMA acc: dist = sqrt(max(0, ni + nj - 2*dot)).
__global__ __launch_bounds__(256, 2)
void gram_kernel(const unsigned short* __restrict__ ebf,
                 const float* __restrict__ nrm,
                 const float* __restrict__ W,
                 float4* __restrict__ part,
                 unsigned int* __restrict__ done,
                 float* __restrict__ out) {
    __shared__ float wlds[2][64 * 128];   // 2 x 32 KB W tiles
    __shared__ float sw_s[4], sdw_s[4], dm_s[4];
    __shared__ double swd[4], sdwd[4];
    __shared__ float dmf[4];
    __shared__ int last_s;

    const int wave = threadIdx.x >> 6;
    const int lane = threadIdx.x & 63;
    const int wRow = wave >> 1;          // 0..1 : i half (64 rows)
    const int wCol = wave & 1;           // 0..1 : j half (32 cols)
    const int i0  = blockIdx.y * 128;
    const int jc0 = blockIdx.x * (JTPB * 64);

    const int lr = lane & 15;
    const int hi = lane >> 4;
    const int lk = hi * 8;

    // Prefetch-lane coords: slot q = r*256 + tid -> row j'=q>>5, slot c=q&31.
    // Source chunk = c ^ (j'&7)  (involution within a 128B window).
    int pj[8], pc[8];
    #pragma unroll
    for (int r = 0; r < 8; ++r) {
        int q = r * 256 + (int)threadIdx.x;
        int jrow = q >> 5;
        pj[r] = jrow;
        pc[r] = ((q & 31) ^ (jrow & 7)) * 4;
    }

    // A fragments (this block's 128 i-rows, wave's 64) + row norms.
    short8 af[4][4];
    #pragma unroll
    for (int kc = 0; kc < 4; ++kc)
        #pragma unroll
        for (int m = 0; m < 4; ++m)
            af[kc][m] = *reinterpret_cast<const short8*>(
                ebf + (size_t)(i0 + wRow * 64 + m * 16 + lr) * DD + kc * 32 + lk);
    f32x4 ni4[4];
    #pragma unroll
    for (int m = 0; m < 4; ++m)
        ni4[m] = *reinterpret_cast<const f32x4*>(nrm + i0 + wRow * 64 + m * 16 + hi * 4);

    __builtin_amdgcn_sched_barrier(0);
    // Prologue: prefetch tile 0 -> buf 0.
    #pragma unroll
    for (int r = 0; r < 8; ++r)
        gld_lds16(W + (size_t)(jc0 + pj[r]) * NN + i0 + pc[r],
                  &wlds[0][r * 1024 + wave * 256]);
    __syncthreads();

    float sW = 0.f, sDW = 0.f, dmax = 0.f;

    for (int t = 0; t < JTPB; ++t) {
        const int j0t = jc0 + t * 64;
        const int jw  = j0t + wCol * 32;
        const int cb  = t & 1;

        // B fragments + col norms — issued BEFORE the prefetch so their
        // vmcnt wait (compiler, before MFMA) leaves the prefetch in flight.
        short8 bf[4][2];
        #pragma unroll
        for (int kc = 0; kc < 4; ++kc)
            #pragma unroll
            for (int n = 0; n < 2; ++n)
                bf[kc][n] = *reinterpret_cast<const short8*>(
                    ebf + (size_t)(jw + n * 16 + lr) * DD + kc * 32 + lk);
        float nj[2];
        #pragma unroll
        for (int n = 0; n < 2; ++n) nj[n] = nrm[jw + n * 16 + lr];

        __builtin_amdgcn_sched_barrier(0);
        // Prefetch tile t+1 -> other buffer (stays in flight through compute).
        if (t + 1 < JTPB) {
            #pragma unroll
            for (int r = 0; r < 8; ++r)
                gld_lds16(W + (size_t)(j0t + 64 + pj[r]) * NN + i0 + pc[r],
                          &wlds[cb ^ 1][r * 1024 + wave * 256]);
        }
        __builtin_amdgcn_sched_barrier(0);

        // Gram MFMA: wave tile 64(i) x 32(j), K=128.
        f32x4 acc[4][2];
        #pragma unroll
        for (int m = 0; m < 4; ++m)
            #pragma unroll
            for (int n = 0; n < 2; ++n) acc[m][n] = (f32x4){0.f, 0.f, 0.f, 0.f};
        #pragma unroll
        for (int kc = 0; kc < 4; ++kc)
            #pragma unroll
            for (int m = 0; m < 4; ++m)
                #pragma unroll
                for (int n = 0; n < 2; ++n)
                    acc[m][n] = __builtin_amdgcn_mfma_f32_16x16x32_bf16(
                        af[kc][m], bf[kc][n], acc[m][n], 0, 0, 0);

        // Epilogue: W^T from LDS (swizzled, bank-even), dist, accumulate.
        #pragma unroll
        for (int m = 0; m < 4; ++m) {
            #pragma unroll
            for (int n = 0; n < 2; ++n) {
                const int jp = wCol * 32 + n * 16 + lr;
                const int c0 = wRow * 16 + m * 4 + hi;
                const f32x4 w4 = *reinterpret_cast<const f32x4*>(
                    &wlds[cb][jp * 128 + ((c0 ^ (jp & 7)) * 4)]);
                #pragma unroll
                for (int r = 0; r < 4; ++r) {
                    float sq = ni4[m][r] + nj[n] - 2.0f * acc[m][n][r];
                    sq = fmaxf(sq, 0.0f);
                    float d = sqrtf(sq);
                    sW  += w4[r];
                    sDW += w4[r] * d;
                    dmax = fmaxf(dmax, d);
                }
            }
        }
        // Drains this wave's prefetch (vmcnt 0) + barrier.
        __syncthreads();
    }

    #pragma unroll
    for (int m = 32; m; m >>= 1) {
        sW  += __shfl_xor(sW, m);
        sDW += __shfl_xor(sDW, m);
        dmax = fmaxf(dmax, __shfl_xor(dmax, m));
    }
    if (lane == 0) { sw_s[wave] = sW; sdw_s[wave] = sDW; dm_s[wave] = dmax; }
    __syncthreads();

    const int bid = blockIdx.y * gridDim.x + blockIdx.x;
    if (threadIdx.x == 0) {
        float SW = 0.f, SDW = 0.f, DM = 0.f;
        #pragma unroll
        for (int k = 0; k < 4; ++k) {
            SW += sw_s[k]; SDW += sdw_s[k]; DM = fmaxf(DM, dm_s[k]);
        }
        float4 p; p.x = SW; p.y = SDW; p.z = DM; p.w = 0.f;
        part[bid] = p;
        __threadfence();                                 // release partial
        unsigned prev = atomicAdd(done, 1u);             // device-scope
        last_s = (prev == NBLK - 1) ? 1 : 0;
    }
    __syncthreads();

    // Last block: fused final reduction (AGENT-scope loads see all partials).
    if (last_s) {
        __threadfence();                                 // acquire
        double SW = 0.0, SDW = 0.0;
        float DM = 0.f;
        for (int idx = threadIdx.x; idx < NBLK; idx += 256) {
            const float* p = reinterpret_cast<const float*>(part + idx);
            float x = __hip_atomic_load(p + 0, __ATOMIC_RELAXED, __HIP_MEMORY_SCOPE_AGENT);
            float y = __hip_atomic_load(p + 1, __ATOMIC_RELAXED, __HIP_MEMORY_SCOPE_AGENT);
            float z = __hip_atomic_load(p + 2, __ATOMIC_RELAXED, __HIP_MEMORY_SCOPE_AGENT);
            SW += (double)x; SDW += (double)y; DM = fmaxf(DM, z);
        }
        #pragma unroll
        for (int m = 32; m; m >>= 1) {
            SW  += __shfl_xor(SW, m);
            SDW += __shfl_xor(SDW, m);
            DM = fmaxf(DM, __shfl_xor(DM, m));
        }
        if (lane == 0) { swd[wave] = SW; sdwd[wave] = SDW; dmf[wave] = DM; }
        __syncthreads();
        if (threadIdx.x == 0) {
            double TSW = 0.0, TSDW = 0.0; float TDM = 0.f;
            #pragma unroll
            for (int k = 0; k < 4; ++k) {
                TSW += swd[k]; TSDW += sdwd[k]; TDM = fmaxf(TDM, dmf[k]);
            }
            out[0] = (float)((TSW - TSDW / (double)TDM) / ((double)NN * (double)NN));
        }
    }
}

extern "C" void kernel_launch(void* const* d_in, const int* in_sizes, int n_in,
                              void* d_out, int out_size, void* d_ws, size_t ws_size,
                              hipStream_t stream) {
    const float* emb = (const float*)d_in[0];
    const float* W   = (const float*)d_in[1];
    float* out = (float*)d_out;

    char* ws = (char*)d_ws;
    float4* part        = (float4*)ws;                               // 8 KB (512 x 16B)
    unsigned int* done  = (unsigned int*)(ws + 8192);                // 4 B counter
    unsigned short* ebf = (unsigned short*)(ws + 16384);             // 2 MB bf16 emb
    float* nrm          = (float*)(ws + 16384 + (size_t)NN * DD * 2);// 32 KB norms

    prep_kernel<<<NN / 4, 256, 0, stream>>>(emb, ebf, nrm, done);
    dim3 grid(NN / (64 * JTPB), NN / 128);   // 8 x 64 = 512 blocks (2/CU)
    gram_kernel<<<grid, 256, 0, stream>>>(ebf, nrm, W, part, done, out);
}

// Round 12
// 83.791 us; speedup vs baseline: 1.9459x; 1.0024x over previous
//
#include <hip/hip_runtime.h>
#include <hip/hip_bf16.h>

#define NN 8192
#define DD 128
#define JTPB 16   // j-tiles (32 wide) per block
#define NBLK 512

typedef __attribute__((ext_vector_type(8))) short short8;
typedef __attribute__((ext_vector_type(4))) float f32x4;

__device__ __forceinline__ unsigned short f2bf(float x) {
    unsigned u = __float_as_uint(x);
    u += 0x7FFFu + ((u >> 16) & 1u);   // round-to-nearest-even
    return (unsigned short)(u >> 16);
}
__device__ __forceinline__ float bf2f(unsigned short b) {
    return __uint_as_float(((unsigned)b) << 16);
}

__device__ __forceinline__ void gld_lds16(const float* src, float* ldst) {
    __builtin_amdgcn_global_load_lds(
        (const __attribute__((address_space(1))) void*)src,
        (__attribute__((address_space(3))) void*)ldst, 16, 0, 0);
}

// Cast emb -> bf16 (ws) and compute row sq-norms FROM THE BF16 VALUES.
// Also zeroes the gram completion counter (stream-ordered before gram).
__global__ void prep_kernel(const float* __restrict__ emb,
                            unsigned short* __restrict__ ebf,
                            float* __restrict__ nrm,
                            unsigned int* __restrict__ done) {
    if (blockIdx.x == 0 && threadIdx.x == 0)
        __hip_atomic_store(done, 0u, __ATOMIC_RELAXED, __HIP_MEMORY_SCOPE_AGENT);
    int row  = blockIdx.x * 4 + (threadIdx.x >> 6);   // 1 wave per row
    int lane = threadIdx.x & 63;
    const float2 v = *reinterpret_cast<const float2*>(emb + (size_t)row * DD + lane * 2);
    unsigned short b0 = f2bf(v.x), b1 = f2bf(v.y);
    ushort2 st; st.x = b0; st.y = b1;
    *reinterpret_cast<ushort2*>(ebf + (size_t)row * DD + lane * 2) = st;
    float f0 = bf2f(b0), f1 = bf2f(b1);
    float s = f0 * f0 + f1 * f1;
    #pragma unroll
    for (int m = 32; m; m >>= 1) s += __shfl_xor(s, m);
    if (lane == 0) nrm[row] = s;
}

// R11 skeleton with tile reshape 128x64 -> 256i x 32j: each W-row visit is
// 1 KB contiguous (vs 512 B) -- DRAM page/interleave efficiency test.
// Each gld_lds instruction fetches exactly one full 1 KB row-chunk.
// 4 waves stacked on i (wave owns 64 i-rows); double-buffered LDS W tiles;
// barriered 1-deep prefetch; fused last-block final reduction.
__global__ __launch_bounds__(256, 2)
void gram_kernel(const unsigned short* __restrict__ ebf,
                 const float* __restrict__ nrm,
                 const float* __restrict__ W,
                 float4* __restrict__ part,
                 unsigned int* __restrict__ done,
                 float* __restrict__ out) {
    __shared__ float wlds[2][32 * 256];   // 2 x 32 KB W tiles ([row][256 f])
    __shared__ float sw_s[4], sdw_s[4], dm_s[4];
    __shared__ double swd[4], sdwd[4];
    __shared__ float dmf[4];
    __shared__ int last_s;

    const int wave = threadIdx.x >> 6;
    const int lane = threadIdx.x & 63;
    const int lr = lane & 15;
    const int hi = lane >> 4;
    const int lk = hi * 8;

    const int i0  = blockIdx.y * 256;               // block's 256 i-cols
    const int jc0 = blockIdx.x * (JTPB * 32);       // block's 512 j-rows

    // Stage: round r stages rows {r*4 + wave}, chunk = lane (16B units),
    // source chunk pre-swizzled: lane ^ (row & 7) (involution per row).
    // One instruction = one full 1 KB contiguous row-chunk.
    auto stage = [&](int j0t, int buf) {
        float* dst = &wlds[buf][0];
        #pragma unroll
        for (int r = 0; r < 8; ++r) {
            const int row = r * 4 + wave;
            const int csw = lane ^ (row & 7);
            gld_lds16(W + (size_t)(j0t + row) * NN + i0 + csw * 4,
                      dst + r * 1024 + wave * 256);
        }
    };

    // A fragments (wave's 64 i-rows) + row norms, cached for all tiles.
    short8 af[4][4];
    #pragma unroll
    for (int kc = 0; kc < 4; ++kc)
        #pragma unroll
        for (int m = 0; m < 4; ++m)
            af[kc][m] = *reinterpret_cast<const short8*>(
                ebf + (size_t)(i0 + wave * 64 + m * 16 + lr) * DD + kc * 32 + lk);
    f32x4 ni4[4];
    #pragma unroll
    for (int m = 0; m < 4; ++m)
        ni4[m] = *reinterpret_cast<const f32x4*>(nrm + i0 + wave * 64 + m * 16 + hi * 4);

    __builtin_amdgcn_sched_barrier(0);
    // Prologue: stage tile 0 -> buf 0.
    stage(jc0, 0);
    __syncthreads();

    float sW = 0.f, sDW = 0.f, dmax = 0.f;

    for (int t = 0; t < JTPB; ++t) {
        const int j0t = jc0 + t * 32;
        const int cb  = t & 1;

        // B fragments + col norms — issued BEFORE the prefetch so their
        // vmcnt wait (compiler, before MFMA) leaves the prefetch in flight.
        short8 bf[4][2];
        #pragma unroll
        for (int kc = 0; kc < 4; ++kc)
            #pragma unroll
            for (int n = 0; n < 2; ++n)
                bf[kc][n] = *reinterpret_cast<const short8*>(
                    ebf + (size_t)(j0t + n * 16 + lr) * DD + kc * 32 + lk);
        float nj[2];
        #pragma unroll
        for (int n = 0; n < 2; ++n) nj[n] = nrm[j0t + n * 16 + lr];

        __builtin_amdgcn_sched_barrier(0);
        // Prefetch tile t+1 -> other buffer (stays in flight through compute).
        if (t + 1 < JTPB) stage(j0t + 32, cb ^ 1);
        __builtin_amdgcn_sched_barrier(0);

        // Gram MFMA: wave tile 64(i) x 32(j), K=128.
        f32x4 acc[4][2];
        #pragma unroll
        for (int m = 0; m < 4; ++m)
            #pragma unroll
            for (int n = 0; n < 2; ++n) acc[m][n] = (f32x4){0.f, 0.f, 0.f, 0.f};
        #pragma unroll
        for (int kc = 0; kc < 4; ++kc)
            #pragma unroll
            for (int m = 0; m < 4; ++m)
                #pragma unroll
                for (int n = 0; n < 2; ++n)
                    acc[m][n] = __builtin_amdgcn_mfma_f32_16x16x32_bf16(
                        af[kc][m], bf[kc][n], acc[m][n], 0, 0, 0);

        // Epilogue: W^T from LDS (swizzled), dist, accumulate.
        #pragma unroll
        for (int m = 0; m < 4; ++m) {
            #pragma unroll
            for (int n = 0; n < 2; ++n) {
                const int jp = n * 16 + lr;                  // LDS row 0..31
                const int c0 = wave * 16 + m * 4 + hi;       // 16B chunk 0..63
                const f32x4 w4 = *reinterpret_cast<const f32x4*>(
                    &wlds[cb][jp * 256 + ((c0 ^ (jp & 7)) * 4)]);
                #pragma unroll
                for (int r = 0; r < 4; ++r) {
                    float sq = ni4[m][r] + nj[n] - 2.0f * acc[m][n][r];
                    sq = fmaxf(sq, 0.0f);
                    float d = sqrtf(sq);
                    sW  += w4[r];
                    sDW += w4[r] * d;
                    dmax = fmaxf(dmax, d);
                }
            }
        }
        // Drains this wave's prefetch (vmcnt 0) + barrier.
        __syncthreads();
    }

    #pragma unroll
    for (int m = 32; m; m >>= 1) {
        sW  += __shfl_xor(sW, m);
        sDW += __shfl_xor(sDW, m);
        dmax = fmaxf(dmax, __shfl_xor(dmax, m));
    }
    if (lane == 0) { sw_s[wave] = sW; sdw_s[wave] = sDW; dm_s[wave] = dmax; }
    __syncthreads();

    const int bid = blockIdx.y * gridDim.x + blockIdx.x;
    if (threadIdx.x == 0) {
        float SW = 0.f, SDW = 0.f, DM = 0.f;
        #pragma unroll
        for (int k = 0; k < 4; ++k) {
            SW += sw_s[k]; SDW += sdw_s[k]; DM = fmaxf(DM, dm_s[k]);
        }
        float4 p; p.x = SW; p.y = SDW; p.z = DM; p.w = 0.f;
        part[bid] = p;
        __threadfence();                                 // release partial
        unsigned prev = atomicAdd(done, 1u);             // device-scope
        last_s = (prev == NBLK - 1) ? 1 : 0;
    }
    __syncthreads();

    // Last block: fused final reduction (AGENT-scope loads see all partials).
    if (last_s) {
        __threadfence();                                 // acquire
        double SW = 0.0, SDW = 0.0;
        float DM = 0.f;
        for (int idx = threadIdx.x; idx < NBLK; idx += 256) {
            const float* p = reinterpret_cast<const float*>(part + idx);
            float x = __hip_atomic_load(p + 0, __ATOMIC_RELAXED, __HIP_MEMORY_SCOPE_AGENT);
            float y = __hip_atomic_load(p + 1, __ATOMIC_RELAXED, __HIP_MEMORY_SCOPE_AGENT);
            float z = __hip_atomic_load(p + 2, __ATOMIC_RELAXED, __HIP_MEMORY_SCOPE_AGENT);
            SW += (double)x; SDW += (double)y; DM = fmaxf(DM, z);
        }
        #pragma unroll
        for (int m = 32; m; m >>= 1) {
            SW  += __shfl_xor(SW, m);
            SDW += __shfl_xor(SDW, m);
            DM = fmaxf(DM, __shfl_xor(DM, m));
        }
        if (lane == 0) { swd[wave] = SW; sdwd[wave] = SDW; dmf[wave] = DM; }
        __syncthreads();
        if (threadIdx.x == 0) {
            double TSW = 0.0, TSDW = 0.0; float TDM = 0.f;
            #pragma unroll
            for (int k = 0; k < 4; ++k) {
                TSW += swd[k]; TSDW += sdwd[k]; TDM = fmaxf(TDM, dmf[k]);
            }
            out[0] = (float)((TSW - TSDW / (double)TDM) / ((double)NN * (double)NN));
        }
    }
}

extern "C" void kernel_launch(void* const* d_in, const int* in_sizes, int n_in,
                              void* d_out, int out_size, void* d_ws, size_t ws_size,
                              hipStream_t stream) {
    const float* emb = (const float*)d_in[0];
    const float* W   = (const float*)d_in[1];
    float* out = (float*)d_out;

    char* ws = (char*)d_ws;
    float4* part        = (float4*)ws;                               // 8 KB (512 x 16B)
    unsigned int* done  = (unsigned int*)(ws + 8192);                // 4 B counter
    unsigned short* ebf = (unsigned short*)(ws + 16384);             // 2 MB bf16 emb
    float* nrm          = (float*)(ws + 16384 + (size_t)NN * DD * 2);// 32 KB norms

    prep_kernel<<<NN / 4, 256, 0, stream>>>(emb, ebf, nrm, done);
    dim3 grid(NN / (32 * JTPB), NN / 256);   // 16 x 32 = 512 blocks (2/CU)
    gram_kernel<<<grid, 256, 0, stream>>>(ebf, nrm, W, part, done, out);
}